// Round 11
// baseline (231.988 us; speedup 1.0000x reference)
//
#include <hip/hip_runtime.h>

// GraphPolicyNetwork: 2-layer GraphSAGE (rank-1 weights -> scalar edge passes)
// + dense head [64x4096]@[4096x4096]. All tensors fp32 (proven round 4).
//
// R21: single change vs R20 (226.4us): agn1/agn2 gather loops register-
// batched 10-deep. R20 diagnosis refined: the gather phase is a per-thread
// DEPENDENT 2-chain (pk[e] -> nf[src] -> LDS atomic) x ~8 iters; block-level
// overlap can't fix per-wave serialization. CAP=2432 <= 10*256 so ONE
// statically-indexed batch covers every bucket: 10 coalesced pk loads, then
// 10 independent gathers (all in flight, latency/10), then the atomics.
// Same pattern scatter_x already uses. Everything else untouched (gemm =
// R11-exact 51us; every rework attempt of it regressed and was reverted).
// Fast path needs 20 MB d_ws; falls back to proven R4 pipeline if smaller.

#define NTOT (64 * 4096)      // 262144 total nodes = 2^18
#define NHID 128
#define GK   4096             // GEMM K == N_NODES
#define KCH  256              // K per chunk
#define KCHUNKS 16
#define NBINS 1024            // dst-range buckets
#define BSZ   256             // nodes per bucket (2^8)
#define BSH   8               // log2(BSZ)
#define CAP   2432            // bucket capacity (mean 2048 + ~8.5 sigma)
#define SCB   256             // scatter blocks
#define GB    10              // gather batch depth (GB*BSZ >= CAP)

typedef unsigned int u32;

__device__ __forceinline__ float fast_tanh(float x) {
    float ax = fabsf(x);
    float t  = __expf(-2.0f * ax);
    float r  = (1.0f - t) * __builtin_amdgcn_rcpf(1.0f + t);
    return copysignf(r, x);
}

// ======================= FAST PATH (ws >= 20 MB) ==========================

// ---- scatter: two-phase per-block reservation into bucket segments ----
// Each thread owns <=8 edges, cached in registers across all 3 phases.
__global__ void __launch_bounds__(1024) scatter_x(const int* __restrict__ src,
                                                  const int* __restrict__ dst,
                                                  int n_edges,
                                                  int* __restrict__ edge_cnt,
                                                  u32* __restrict__ packed) {
    __shared__ int lc[NBINS];
    __shared__ int lbase[NBINS];
    int t = threadIdx.x;
    lc[t] = 0;                 // NBINS == 1024 == blockDim.x
    __syncthreads();
    int per = (n_edges + gridDim.x - 1) / gridDim.x;   // <= 8192
    int e0 = blockIdx.x * per;
    int e1 = min(e0 + per, n_edges);

    int dreg[8], sreg[8];
#pragma unroll
    for (int i = 0; i < 8; ++i) {
        int e = e0 + t + i * 1024;
        bool ok = e < e1;
        int d = ok ? dst[e] : -1;
        dreg[i] = d;
        sreg[i] = ok ? src[e] : 0;
        if (ok) atomicAdd(&lc[d >> BSH], 1);
    }
    __syncthreads();
    lbase[t] = atomicAdd(&edge_cnt[t], lc[t]);
    lc[t] = 0;
    __syncthreads();
#pragma unroll
    for (int i = 0; i < 8; ++i) {
        int d = dreg[i];
        if (d >= 0) {
            int b = d >> BSH;
            int pos = lbase[b] + atomicAdd(&lc[b], 1);
            if (pos < CAP)                    // p(overflow) ~ 0, fixed graph
                packed[(size_t)b * CAP + pos] =
                    ((u32)(d & (BSZ - 1)) << 18) | (u32)sreg[i];
        }
    }
}

// ---- fused agg1+node1: batched LDS histogram + per-node layer-1/2 math ----
// One 256-thr block per bucket; thread t = node t. Gather batched 10-deep:
// all pk loads issued, then all nf gathers in flight, then atomics.
__global__ void __launch_bounds__(256) agn1_x(const u32* __restrict__ packed,
                                              const int* __restrict__ edge_cnt,
                                              const float* __restrict__ nf,
                                              const float* __restrict__ w_s1,
                                              const float* __restrict__ w_n1,
                                              const float* __restrict__ bb1,
                                              const float* __restrict__ w_s2,
                                              const float* __restrict__ w_n2,
                                              float* __restrict__ degf,
                                              float* __restrict__ selfp,
                                              float* __restrict__ sp) {
    __shared__ float lsum[BSZ];
    __shared__ float lcnt[BSZ];
    __shared__ float lws1[NHID], lwn1[NHID], lb1[NHID], lws2[NHID], lwn2[NHID];
    int t = threadIdx.x;
    int b = blockIdx.x;
    lsum[t] = 0.0f;
    lcnt[t] = 0.0f;
    if (t < NHID) {
        lws1[t] = w_s1[t];
        lwn1[t] = w_n1[t];
        lb1[t]  = bb1[t];
        lws2[t] = w_s2[t];
        lwn2[t] = w_n2[t];
    }
    __syncthreads();
    int en = min(edge_cnt[b], CAP);
    const u32* pk = packed + (size_t)b * CAP;

    u32  pr[GB];
    float gv[GB];
#pragma unroll
    for (int i = 0; i < GB; ++i) {
        int e = t + i * BSZ;
        pr[i] = (e < en) ? pk[e] : 0xFFFFFFFFu;
    }
#pragma unroll
    for (int i = 0; i < GB; ++i)
        gv[i] = (pr[i] != 0xFFFFFFFFu) ? nf[pr[i] & 0x3FFFFu] : 0.0f;
#pragma unroll
    for (int i = 0; i < GB; ++i) {
        if (pr[i] != 0xFFFFFFFFu) {
            int local = (int)(pr[i] >> 18);
            atomicAdd(&lsum[local], gv[i]);
            atomicAdd(&lcnt[local], 1.0f);
        }
    }
    __syncthreads();

    int v = b * BSZ + t;
    float cf = lcnt[t];
    float hn = lsum[t] / fmaxf(cf, 1.0f);
    float f  = nf[v];
    float a = 0.0f, s2 = 0.0f;
#pragma unroll 8
    for (int j = 0; j < NHID; ++j) {
        float th = fast_tanh(fmaf(f, lws1[j], fmaf(hn, lwn1[j], lb1[j])));
        a  = fmaf(th, lws2[j], a);
        s2 = fmaf(th, lwn2[j], s2);
    }
    degf[v]  = cf;
    selfp[v] = a;
    sp[v]    = s2;
}

// ---- fused agg2+node2: batched LDS histogram + out1 / h2t epilogue ----
__global__ void __launch_bounds__(256) agn2_x(const u32* __restrict__ packed,
                                              const int* __restrict__ edge_cnt,
                                              const float* __restrict__ spv,
                                              const float* __restrict__ selfp,
                                              const float* __restrict__ degf,
                                              const float* __restrict__ b2p,
                                              float* __restrict__ out1,
                                              float* __restrict__ h2t) {
    __shared__ float lsum[BSZ];
    int t = threadIdx.x;
    int b = blockIdx.x;
    lsum[t] = 0.0f;
    __syncthreads();
    int en = min(edge_cnt[b], CAP);
    const u32* pk = packed + (size_t)b * CAP;

    u32  pr[GB];
    float gv[GB];
#pragma unroll
    for (int i = 0; i < GB; ++i) {
        int e = t + i * BSZ;
        pr[i] = (e < en) ? pk[e] : 0xFFFFFFFFu;
    }
#pragma unroll
    for (int i = 0; i < GB; ++i)
        gv[i] = (pr[i] != 0xFFFFFFFFu) ? spv[pr[i] & 0x3FFFFu] : 0.0f;
#pragma unroll
    for (int i = 0; i < GB; ++i) {
        if (pr[i] != 0xFFFFFFFFu)
            atomicAdd(&lsum[pr[i] >> 18], gv[i]);
    }
    __syncthreads();

    int v = b * BSZ + t;
    float o = selfp[v] + lsum[t] / fmaxf(degf[v], 1.0f) + b2p[0];
    out1[v] = o;
    int r = v >> 12;     // graph (row) index 0..63
    int k = v & 4095;    // node-in-graph (K) index
    h2t[k * 64 + r] = fast_tanh(o);
}

// ---- GEMM (R11 exact, proven 49-52us): 64x64 tile, 8 waves x 8 rows ----
__global__ void __launch_bounds__(512, 4) gemm_x(const float* __restrict__ h2t,
                                                 const float* __restrict__ w3,
                                                 float* __restrict__ Cpart) {
    int lane = threadIdx.x & 63;
    int wv   = threadIdx.x >> 6;          // 0..7
    int col  = blockIdx.x * 64 + lane;
    int k0   = blockIdx.y * KCH;
    int row0 = __builtin_amdgcn_readfirstlane(wv * 8);

    const float* Ap = h2t + (size_t)k0 * 64 + row0;
    const float* wp = w3 + (size_t)k0 * GK + col;

    float acc[8];
#pragma unroll
    for (int r = 0; r < 8; ++r) acc[r] = 0.0f;

    float bvA[8], bvB[8];
    float avA[8], avB[8];

#pragma unroll
    for (int j = 0; j < 8; ++j) bvA[j] = wp[(size_t)j * GK];
#pragma unroll
    for (int r = 0; r < 8; ++r) avA[r] = Ap[r];

    for (int kk = 0; kk < KCH; kk += 16) {
#pragma unroll
        for (int j = 0; j < 8; ++j) bvB[j] = wp[(size_t)(kk + 8 + j) * GK];
#pragma unroll
        for (int j = 0; j < 8; ++j) {
            const float* An = Ap + (size_t)(kk + j + 1) * 64;
            if ((j & 1) == 0) {
#pragma unroll
                for (int r = 0; r < 8; ++r) avB[r] = An[r];
                float b = bvA[j];
#pragma unroll
                for (int r = 0; r < 8; ++r) acc[r] = fmaf(avA[r], b, acc[r]);
            } else {
#pragma unroll
                for (int r = 0; r < 8; ++r) avA[r] = An[r];
                float b = bvA[j];
#pragma unroll
                for (int r = 0; r < 8; ++r) acc[r] = fmaf(avB[r], b, acc[r]);
            }
        }
        if (kk + 16 < KCH) {
#pragma unroll
            for (int j = 0; j < 8; ++j) bvA[j] = wp[(size_t)(kk + 16 + j) * GK];
        }
#pragma unroll
        for (int j = 0; j < 8; ++j) {
            int kn = kk + 8 + j + 1;
            if (kn > KCH - 1) kn = KCH - 1;
            const float* An = Ap + (size_t)kn * 64;
            if ((j & 1) == 0) {
#pragma unroll
                for (int r = 0; r < 8; ++r) avB[r] = An[r];
                float b = bvB[j];
#pragma unroll
                for (int r = 0; r < 8; ++r) acc[r] = fmaf(avA[r], b, acc[r]);
            } else {
#pragma unroll
                for (int r = 0; r < 8; ++r) avA[r] = An[r];
                float b = bvB[j];
#pragma unroll
                for (int r = 0; r < 8; ++r) acc[r] = fmaf(avB[r], b, acc[r]);
            }
        }
    }

    float* Cp = Cpart + (size_t)blockIdx.y * NTOT + (size_t)row0 * GK + col;
#pragma unroll
    for (int r = 0; r < 8; ++r) Cp[(size_t)r * GK] = acc[r];
}

// ---- reduce K-chunk partials + b3 -> out2 (float4) ----
__global__ void reduce_x(const float4* __restrict__ Cpart, const float4* __restrict__ b3v,
                         float4* __restrict__ out2) {
    int v = blockIdx.x * blockDim.x + threadIdx.x;   // float4 index, NTOT/4
    float4 s = b3v[v & 1023];
#pragma unroll
    for (int kc = 0; kc < KCHUNKS; ++kc) {
        float4 c = Cpart[(size_t)kc * (NTOT / 4) + v];
        s.x += c.x; s.y += c.y; s.z += c.z; s.w += c.w;
    }
    out2[v] = s;
}

// ================== FALLBACK PATH (proven R4 pipeline) ====================

__global__ void edge_pass1_f(const int* __restrict__ src, const int* __restrict__ dst,
                             const float* __restrict__ nf, float* __restrict__ agg,
                             float* __restrict__ deg, int n_edges) {
    int e = blockIdx.x * blockDim.x + threadIdx.x;
    if (e >= n_edges) return;
    int s = src[e], d = dst[e];
    atomicAdd(&agg[d], nf[s]);
    atomicAdd(&deg[d], 1.0f);
}

__global__ void node1_f(const float* __restrict__ nf, float* s0,
                        const float* __restrict__ deg,
                        const float* __restrict__ w_s1, const float* __restrict__ w_n1,
                        const float* __restrict__ bb1,
                        const float* __restrict__ w_s2, const float* __restrict__ w_n2,
                        float* __restrict__ sp) {
    __shared__ float lws1[NHID], lwn1[NHID], lb1[NHID], lws2[NHID], lwn2[NHID];
    int tid = threadIdx.x;
    if (tid < NHID) {
        lws1[tid] = w_s1[tid];
        lwn1[tid] = w_n1[tid];
        lb1[tid]  = bb1[tid];
        lws2[tid] = w_s2[tid];
        lwn2[tid] = w_n2[tid];
    }
    __syncthreads();
    int v = blockIdx.x * blockDim.x + tid;
    float f  = nf[v];
    float hn = s0[v] / fmaxf(deg[v], 1.0f);
    float a = 0.0f, s = 0.0f;
#pragma unroll 8
    for (int j = 0; j < NHID; ++j) {
        float t = fast_tanh(fmaf(f, lws1[j], fmaf(hn, lwn1[j], lb1[j])));
        a = fmaf(t, lws2[j], a);
        s = fmaf(t, lwn2[j], s);
    }
    s0[v] = a;
    sp[v] = s;
}

__global__ void edge_pass2_f(const int* __restrict__ src, const int* __restrict__ dst,
                             const float* __restrict__ sp, float* __restrict__ agg2,
                             int n_edges) {
    int e = blockIdx.x * blockDim.x + threadIdx.x;
    if (e >= n_edges) return;
    atomicAdd(&agg2[dst[e]], sp[src[e]]);
}

__global__ void node2_f(const float* __restrict__ s0, const float* __restrict__ agg2,
                        const float* __restrict__ deg, const float* __restrict__ b2p,
                        const float* __restrict__ b3p,
                        float* __restrict__ out1, float* __restrict__ h2t,
                        float* __restrict__ out2) {
    int v = blockIdx.x * blockDim.x + threadIdx.x;
    float o = s0[v] + agg2[v] / fmaxf(deg[v], 1.0f) + b2p[0];
    out1[v] = o;
    int r = v >> 12;
    int k = v & 4095;
    h2t[k * 64 + r] = fast_tanh(o);
    out2[v] = b3p[v & 4095];
}

__global__ void __launch_bounds__(256) gemm_f(const float* __restrict__ h2t,
                                              const float* __restrict__ w3,
                                              float* __restrict__ out2) {
    int n  = blockIdx.x * 256 + threadIdx.x;
    int k0 = blockIdx.y * KCH;
    float acc[64];
#pragma unroll
    for (int r = 0; r < 64; ++r) acc[r] = 0.0f;
    for (int k = k0; k < k0 + KCH; ++k) {
        float bv = w3[(size_t)k * GK + n];
        const float* Ak = h2t + k * 64;
#pragma unroll
        for (int r = 0; r < 64; ++r) acc[r] = fmaf(Ak[r], bv, acc[r]);
    }
#pragma unroll
    for (int r = 0; r < 64; ++r) atomicAdd(&out2[r * GK + n], acc[r]);
}

// ==========================================================================

extern "C" void kernel_launch(void* const* d_in, const int* in_sizes, int n_in,
                              void* d_out, int out_size, void* d_ws, size_t ws_size,
                              hipStream_t stream) {
    const float* nf  = (const float*)d_in[0];
    const int*   src = (const int*)d_in[1];
    const int*   dst = (const int*)d_in[2];
    const float* ws1 = (const float*)d_in[3];
    const float* wn1 = (const float*)d_in[4];
    const float* b1  = (const float*)d_in[5];
    const float* ws2 = (const float*)d_in[6];
    const float* wn2 = (const float*)d_in[7];
    const float* b2  = (const float*)d_in[8];
    const float* w3  = (const float*)d_in[9];
    const float* b3  = (const float*)d_in[10];
    float* out1 = (float*)d_out;
    float* out2 = (float*)d_out + NTOT;

    int n_edges = in_sizes[1];
    int eb = (n_edges + 255) / 256;

    if (ws_size >= (size_t)20 * 1024 * 1024 && n_edges <= (1 << 21)) {
        // -------- fast path: 20 MB layout --------
        // packed  [0, 9.97M)  (NBINS*CAP u32 = 9961472 B)
        // degf    [10M, 11M)  selfp [11M, 12M)  sp [12M, 13M)
        // h2t     [16M, 17M)
        // edge_cnt @ 17M      (NBINS ints = 4 KB)
        // Cpart overlays [0, 16M): packed/degf/selfp/sp dead when gemm runs;
        // h2t at 16M is outside Cpart (ends exactly at 16777216).
        char*  base     = (char*)d_ws;
        u32*   packed   = (u32*)base;
        float* degf     = (float*)(base + 10485760);
        float* selfp    = (float*)(base + 11534336);
        float* spbuf    = (float*)(base + 12582912);
        float* h2t      = (float*)(base + 16777216);
        int*   edge_cnt = (int*)(base + 17825792);
        float* Cpart    = (float*)base;

        (void)hipMemsetAsync(edge_cnt, 0, NBINS * sizeof(int), stream);
        scatter_x<<<SCB, 1024, 0, stream>>>(src, dst, n_edges, edge_cnt, packed);
        agn1_x<<<NBINS, BSZ, 0, stream>>>(packed, edge_cnt, nf, ws1, wn1, b1,
                                          ws2, wn2, degf, selfp, spbuf);
        agn2_x<<<NBINS, BSZ, 0, stream>>>(packed, edge_cnt, spbuf, selfp, degf,
                                          b2, out1, h2t);
        gemm_x<<<dim3(GK / 64, KCHUNKS), 512, 0, stream>>>(h2t, w3, Cpart);
        reduce_x<<<NTOT / 4 / 256, 256, 0, stream>>>((const float4*)Cpart,
                                                     (const float4*)b3, (float4*)out2);
    } else {
        // -------- fallback: proven R4 pipeline (4.19 MB) --------
        float* ws = (float*)d_ws;
        float* S0 = ws;            // agg -> selfpart
        float* S1 = ws + 1 * NTOT; // deg
        float* S2 = ws + 2 * NTOT; // agg2
        float* S3 = ws + 3 * NTOT; // sp -> h2t

        (void)hipMemsetAsync(S0, 0, (size_t)3 * NTOT * sizeof(float), stream);
        edge_pass1_f<<<eb, 256, 0, stream>>>(src, dst, nf, S0, S1, n_edges);
        node1_f<<<NTOT / 256, 256, 0, stream>>>(nf, S0, S1, ws1, wn1, b1, ws2, wn2, S3);
        edge_pass2_f<<<eb, 256, 0, stream>>>(src, dst, S3, S2, n_edges);
        node2_f<<<NTOT / 256, 256, 0, stream>>>(S0, S2, S1, b2, b3, out1, S3, out2);
        gemm_f<<<dim3(GK / 256, KCHUNKS), 256, 0, stream>>>(S3, w3, out2);
    }
}